// Round 7
// baseline (133.722 us; speedup 1.0000x reference)
//
#include <hip/hip_runtime.h>
#include <hip/hip_bf16.h>

#define NB 8
#define LQ 4096
#define SK 4096
#define NH 8
#define DD 64
#define NPAIR (NB*NH)        // 64 (n,h) pairs
#define KVSZ (DD*DD + DD)    // 4160: 64x64 KV + 64 Ksum
#define VSP 2                // v-split: each block computes 32 of 64 v-cols
#define FRAGW 768            // uint4 words of prepacked fragments per pair (12KB)

typedef short v8s __attribute__((ext_vector_type(8)));   // 8 bf16 MFMA operand
typedef float v4f __attribute__((ext_vector_type(4)));   // MFMA accumulator
union U8 { v8s s; unsigned int u[4]; uint4 q; };

__device__ __forceinline__ float fmap(float x) {
    return x > 0.f ? x + 1.f : __expf(x);   // elu+1
}
__device__ __forceinline__ unsigned short bf_hi(float x) {  // RNE fp32->bf16
    unsigned int u = __float_as_uint(x);
    return (unsigned short)((u + 0x7FFFu + ((u >> 16) & 1u)) >> 16);
}
__device__ __forceinline__ float bf_f(unsigned short b) {
    return __uint_as_float(((unsigned int)b) << 16);
}
// hi/lo bf16 split of (x0,x1) via v_cvt_pk_bf16_f32 (RNE, bit-identical to bf_hi):
// .x = hi(x0) | hi(x1)<<16 ; .y = lo(x0) | lo(x1)<<16
__device__ __forceinline__ uint2 packsplit2(float x0, float x1) {
    union { __hip_bfloat162 b; unsigned int u; } h, l;
    h.b = __float22bfloat162_rn(make_float2(x0, x1));
    float r0 = x0 - __uint_as_float(h.u << 16);
    float r1 = x1 - __uint_as_float(h.u & 0xFFFF0000u);
    l.b = __float22bfloat162_rn(make_float2(r0, r1));
    uint2 r; r.x = h.u; r.y = l.u;
    return r;
}
__device__ __forceinline__ int swzp(int d, int sp) {
    return (d * 16 + sp) ^ (((d >> 2) & 1) << 4);
}
#define MFMA(A, B, C) __builtin_amdgcn_mfma_f32_16x16x32_bf16((A), (B), (C), 0, 0, 0)

// ---------------- Phase 1: partial KV = K^T V (+ ones-col => Ksum) via MFMA --------
// 2 waves, wave-private tiles; 2-deep register prefetch hides HBM latency
// (~3000 cyc window vs ~900 cyc latency); cvt_pk-based hi/lo packing.
__global__ __launch_bounds__(128, 3) void kv_partial_kernel(
    const float* __restrict__ K, const float* __restrict__ V,
    const float* __restrict__ kvm, float* __restrict__ partial, int CH)
{
    int bx = blockIdx.x;
    int chunk = bx % CH;
    int vh    = (bx / CH) % VSP;
    int pair  = bx / (CH * VSP);
    int nb = pair >> 3, h = pair & 7;
    int tid = threadIdx.x, w = tid >> 6, lane = tid & 63;
    int g = lane >> 4, c16 = lane & 15;
    int sp = lane & 15, dq = lane >> 4;    // staging roles

    __shared__ unsigned int smem[2][3072];
    __shared__ float ksb[2][64];
    unsigned int* kpl = &smem[w][0];
    unsigned int* vpl = &smem[w][2048];

    v4f acc[4][2], ks4[4];
    v4f z4 = {0.f, 0.f, 0.f, 0.f};
#pragma unroll
    for (int i = 0; i < 4; ++i) {
        ks4[i] = z4; acc[i][0] = z4; acc[i][1] = z4;
    }
    U8 Bones;
#pragma unroll
    for (int p = 0; p < 4; ++p) Bones.u[p] = (c16 == 0) ? 0x3F803F80u : 0u;

    int SC = SK / CH;
    int tiles = SC >> 5;
    int nk = tiles >> 1;          // tiles per wave (it = w + 2k)

    auto LOADG = [&](float4 (&kr)[8], float4 (&vr)[4], float& m0, float& m1, int it) {
        int s0 = chunk * SC + (it << 5);
        int row = nb * SK + s0 + 2 * sp;
        m0 = kvm[row]; m1 = kvm[row + 1];
        const float* kb = K + ((size_t)row * NH + h) * DD;
        const float* vb = V + ((size_t)row * NH + h) * DD + vh * 32;
#pragma unroll
        for (int c = 0; c < 4; ++c) {
            kr[2 * c]     = *(const float4*)(kb + dq * 4 + c * 16);
            kr[2 * c + 1] = *(const float4*)(kb + NH * DD + dq * 4 + c * 16);
        }
#pragma unroll
        for (int c = 0; c < 2; ++c) {
            vr[2 * c]     = *(const float4*)(vb + dq * 4 + c * 16);
            vr[2 * c + 1] = *(const float4*)(vb + NH * DD + dq * 4 + c * 16);
        }
    };

    auto PACKW = [&](const float4 (&kr)[8], const float4 (&vr)[4], float m0, float m1) {
#pragma unroll
        for (int c = 0; c < 4; ++c) {
            float x0[4] = {kr[2*c].x, kr[2*c].y, kr[2*c].z, kr[2*c].w};
            float x1[4] = {kr[2*c+1].x, kr[2*c+1].y, kr[2*c+1].z, kr[2*c+1].w};
#pragma unroll
            for (int i = 0; i < 4; ++i) {
                uint2 pw = packsplit2(fmap(x0[i]) * m0, fmap(x1[i]) * m1);
                int idx = swzp(dq * 4 + c * 16 + i, sp);
                kpl[idx] = pw.x;
                kpl[1024 + idx] = pw.y;
            }
        }
#pragma unroll
        for (int c = 0; c < 2; ++c) {
            float x0[4] = {vr[2*c].x, vr[2*c].y, vr[2*c].z, vr[2*c].w};
            float x1[4] = {vr[2*c+1].x, vr[2*c+1].y, vr[2*c+1].z, vr[2*c+1].w};
#pragma unroll
            for (int i = 0; i < 4; ++i) {
                uint2 pw = packsplit2(x0[i] * m0, x1[i] * m1);
                int idx = swzp(dq * 4 + c * 16 + i, sp);
                vpl[idx] = pw.x;
                vpl[512 + idx] = pw.y;
            }
        }
    };

    auto COMPUTE = [&]() {
        v8s bh[2], bl[2];
#pragma unroll
        for (int nn = 0; nn < 2; ++nn) {
            int vloc = 16 * nn + c16;
            int idx = (vloc * 16 + 4 * g) ^ (((vloc >> 2) & 1) << 4);
            bh[nn] = *(const v8s*)&vpl[idx];
            bl[nn] = *(const v8s*)&vpl[512 + idx];
        }
#pragma unroll
        for (int md = 0; md < 4; ++md) {
            int d = 16 * md + c16;
            int idx = (d * 16 + 4 * g) ^ (((d >> 2) & 1) << 4);
            v8s ah = *(const v8s*)&kpl[idx];
            v8s al = *(const v8s*)&kpl[1024 + idx];
            if (vh == 0) {
                ks4[md] = MFMA(ah, Bones.s, ks4[md]);
                ks4[md] = MFMA(al, Bones.s, ks4[md]);
            }
#pragma unroll
            for (int nn = 0; nn < 2; ++nn) {
                acc[md][nn] = MFMA(ah, bh[nn], acc[md][nn]);
                acc[md][nn] = MFMA(al, bh[nn], acc[md][nn]);
                acc[md][nn] = MFMA(ah, bl[nn], acc[md][nn]);
            }
        }
    };

    float4 kr0[8], vr0[4], kr1[8], vr1[4];
    float m00, m01, m10, m11;

    LOADG(kr0, vr0, m00, m01, w);
    if (nk > 1) LOADG(kr1, vr1, m10, m11, w + 2);
    for (int k = 0; k < nk; k += 2) {
        PACKW(kr0, vr0, m00, m01);
        if (k + 2 < nk) LOADG(kr0, vr0, m00, m01, w + 2 * (k + 2));
        COMPUTE();
        if (k + 1 < nk) {
            PACKW(kr1, vr1, m10, m11);
            if (k + 3 < nk) LOADG(kr1, vr1, m10, m11, w + 2 * (k + 3));
            COMPUTE();
        }
    }

    // ---- epilogue: cross-wave reduce, write partial ----
    float* dst = partial + ((size_t)chunk * NPAIR + pair) * KVSZ;
    if (vh == 0 && c16 == 0) {
#pragma unroll
        for (int md = 0; md < 4; ++md)
#pragma unroll
            for (int jj = 0; jj < 4; ++jj)
                ksb[w][16 * md + 4 * g + jj] = ks4[md][jj];
    }
    __syncthreads();
    if (vh == 0 && tid < 64) dst[4096 + tid] = ksb[0][tid] + ksb[1][tid];

    float* scr = (float*)&smem[0][0];
#pragma unroll
    for (int md = 0; md < 4; ++md)
#pragma unroll
        for (int nn = 0; nn < 2; ++nn)
#pragma unroll
            for (int jj = 0; jj < 4; ++jj)
                scr[w * 2048 + (16 * md + 4 * g + jj) * 32 + 16 * nn + c16] = acc[md][nn][jj];
    __syncthreads();
    {
        int i0 = tid * 16;
#pragma unroll
        for (int e = 0; e < 4; ++e) {
            int idx = i0 + 4 * e;
            float4 x = *(float4*)&scr[idx];
            float4 y = *(float4*)&scr[2048 + idx];
            int d = idx >> 5, v = idx & 31;
            *(float4*)&dst[d * 64 + vh * 32 + v] =
                make_float4(x.x + y.x, x.y + y.y, x.z + y.z, x.w + y.w);
        }
    }
}

// ---------------- Phase 1b: reduce partials over chunks -----------------
__global__ __launch_bounds__(256) void kv_reduce_kernel(
    const float* __restrict__ partial, float* __restrict__ kvf, int CH)
{
    int i = blockIdx.x * 256 + threadIdx.x;
    if (i >= NPAIR * KVSZ) return;
    float s = 0.f;
    for (int c = 0; c < CH; ++c) s += partial[(size_t)c * NPAIR * KVSZ + i];
    kvf[i] = s;
}

// ---------------- Phase 1c: prepack B fragments (bf16) for attn_out --------
__global__ __launch_bounds__(256) void kv_pack_kernel(
    const float* __restrict__ kvf, uint4* __restrict__ frag)
{
    int pair = blockIdx.x;
    int t = threadIdx.x;
    __shared__ float kvr[KVSZ];
    const float* src = kvf + (size_t)pair * KVSZ;
    for (int e = t; e < KVSZ / 4; e += 256)
        *(float4*)&kvr[4 * e] = *(const float4*)(src + 4 * e);
    __syncthreads();

    for (int e = t; e < FRAGW; e += 256) {
        int i4 = e >> 6, lane = e & 63;
        int g = lane >> 4, c16 = lane & 15;
        unsigned int wd[4];
        if (i4 < 8) {
            int ks = i4 >> 2, nn = i4 & 3;
#pragma unroll
            for (int p = 0; p < 4; ++p) {
                float x0 = kvr[(32 * ks + 8 * g + 2 * p) * 64 + 16 * nn + c16];
                float x1 = kvr[(32 * ks + 8 * g + 2 * p + 1) * 64 + 16 * nn + c16];
                wd[p] = (unsigned int)bf_hi(x0) | ((unsigned int)bf_hi(x1) << 16);
            }
        } else {
            int j = i4 - 8, ks = j & 1, lo = j >> 1;
#pragma unroll
            for (int p = 0; p < 4; ++p) {
                unsigned int wp = 0;
                if (c16 == 0) {
                    float x0 = kvr[4096 + 32 * ks + 8 * g + 2 * p];
                    float x1 = kvr[4096 + 32 * ks + 8 * g + 2 * p + 1];
                    unsigned short h0 = bf_hi(x0), h1 = bf_hi(x1);
                    if (lo)
                        wp = (unsigned int)bf_hi(x0 - bf_f(h0)) |
                             ((unsigned int)bf_hi(x1 - bf_f(h1)) << 16);
                    else
                        wp = (unsigned int)h0 | ((unsigned int)h1 << 16);
                }
                wd[p] = wp;
            }
        }
        uint4 o; o.x = wd[0]; o.y = wd[1]; o.z = wd[2]; o.w = wd[3];
        frag[(size_t)pair * FRAGW + e] = o;
    }
}

// ---------------- Phase 2: out = (q.KV)/(q.Ksum + eps) via MFMA, no LDS --------
__global__ __launch_bounds__(256) void attn_out_kernel(
    const float* __restrict__ Q, const float* __restrict__ qm,
    const uint4* __restrict__ frag, float* __restrict__ out)
{
    int bx = blockIdx.x;
    int pair = bx >> 5;            // 32 consecutive blocks share a pair (L2)
    int rb   = bx & 31;            // 128-row group
    int nb = pair >> 3, h = pair & 7;
    int lane = threadIdx.x & 63;
    int w    = threadIdx.x >> 6;
    int g    = lane >> 4;
    int c16  = lane & 15;

    const uint4* fb = frag + (size_t)pair * FRAGW;
    U8 Bh[2][4], Bkh[2], Bkl[2];
#pragma unroll
    for (int ks = 0; ks < 2; ++ks)
#pragma unroll
        for (int nn = 0; nn < 4; ++nn)
            Bh[ks][nn].q = fb[(ks * 4 + nn) * 64 + lane];
    Bkh[0].q = fb[8 * 64 + lane];
    Bkh[1].q = fb[9 * 64 + lane];
    Bkl[0].q = fb[10 * 64 + lane];
    Bkl[1].q = fb[11 * 64 + lane];

    float4 qA[2][4];
    float qmA[2];

    auto QLOAD = [&](int it, float4* qr, float& qmv) {
        int row = rb * 128 + (w + 4 * it) * 16 + c16;
        qmv = qm[nb * LQ + row];
        const float* qrow = Q + ((size_t)((nb * LQ + row) * NH + h)) * DD;
        qr[0] = *(const float4*)(qrow + 8 * g);
        qr[1] = *(const float4*)(qrow + 8 * g + 4);
        qr[2] = *(const float4*)(qrow + 8 * g + 32);
        qr[3] = *(const float4*)(qrow + 8 * g + 36);
    };

    v4f z4 = {0.f, 0.f, 0.f, 0.f};
    QLOAD(0, qA[0], qmA[0]);
#pragma unroll
    for (int it = 0; it < 2; ++it) {
        if (it == 0) QLOAD(1, qA[1], qmA[1]);   // prefetch under pack+MFMA
        const float4* qr = qA[it];
        float qmv = qmA[it];

        U8 Ah[2], Al[2];
#pragma unroll
        for (int ks = 0; ks < 2; ++ks) {
            float qv[8] = {qr[2*ks].x, qr[2*ks].y, qr[2*ks].z, qr[2*ks].w,
                           qr[2*ks+1].x, qr[2*ks+1].y, qr[2*ks+1].z, qr[2*ks+1].w};
#pragma unroll
            for (int p = 0; p < 4; ++p) {
                uint2 pw = packsplit2(fmap(qv[2*p]) * qmv, fmap(qv[2*p+1]) * qmv);
                Ah[ks].u[p] = pw.x;
                Al[ks].u[p] = pw.y;
            }
        }

        v4f a0 = z4, a1 = z4, a2 = z4, a3 = z4, a4 = z4;
#pragma unroll
        for (int ks = 0; ks < 2; ++ks) {
            a0 = MFMA(Ah[ks].s, Bh[ks][0].s, a0);
            a1 = MFMA(Ah[ks].s, Bh[ks][1].s, a1);
            a2 = MFMA(Ah[ks].s, Bh[ks][2].s, a2);
            a3 = MFMA(Ah[ks].s, Bh[ks][3].s, a3);
            a0 = MFMA(Al[ks].s, Bh[ks][0].s, a0);
            a1 = MFMA(Al[ks].s, Bh[ks][1].s, a1);
            a2 = MFMA(Al[ks].s, Bh[ks][2].s, a2);
            a3 = MFMA(Al[ks].s, Bh[ks][3].s, a3);
            a4 = MFMA(Ah[ks].s, Bkh[ks].s, a4);
            a4 = MFMA(Al[ks].s, Bkh[ks].s, a4);
            a4 = MFMA(Ah[ks].s, Bkl[ks].s, a4);
        }

        int row0 = rb * 128 + (w + 4 * it) * 16;
        int src = lane & 48;
#pragma unroll
        for (int jj = 0; jj < 4; ++jj) {
            float den = __shfl(a4[jj], src);
            float z = 1.f / (den + 1e-6f);
            size_t ob = ((size_t)((nb * LQ + row0 + 4 * g + jj) * NH + h)) * DD + c16;
            out[ob]      = a0[jj] * z;
            out[ob + 16] = a1[jj] * z;
            out[ob + 32] = a2[jj] * z;
            out[ob + 48] = a3[jj] * z;
        }
    }
}

extern "C" void kernel_launch(void* const* d_in, const int* in_sizes, int n_in,
                              void* d_out, int out_size, void* d_ws, size_t ws_size,
                              hipStream_t stream) {
    const float* Q   = (const float*)d_in[0];
    const float* K   = (const float*)d_in[1];
    const float* V   = (const float*)d_in[2];
    const float* qm  = (const float*)d_in[3];
    const float* kvm = (const float*)d_in[4];
    float* out = (float*)d_out;

    int CH = 16;
    while (CH > 1 && (size_t)(CH + 1) * NPAIR * KVSZ * sizeof(float) > ws_size) CH >>= 1;

    float* partial = (float*)d_ws;
    float* kvf = partial + (size_t)CH * NPAIR * KVSZ;
    // frag overlays partial slab 0 (partial is dead once kv_reduce has run)
    uint4* frag = (uint4*)d_ws;

    kv_partial_kernel<<<dim3(NPAIR * CH * VSP), dim3(128), 0, stream>>>(K, V, kvm, partial, CH);
    kv_reduce_kernel<<<dim3((NPAIR * KVSZ + 255) / 256), dim3(256), 0, stream>>>(partial, kvf, CH);
    kv_pack_kernel<<<dim3(NPAIR), dim3(256), 0, stream>>>(kvf, frag);
    attn_out_kernel<<<dim3(NPAIR * 32), dim3(256), 0, stream>>>(Q, qm, frag, out);
}

// Round 8
// 103.941 us; speedup vs baseline: 1.2865x; 1.2865x over previous
//
#include <hip/hip_runtime.h>
#include <hip/hip_bf16.h>

#define NB 8
#define LQ 4096
#define SK 4096
#define NH 8
#define DD 64
#define NPAIR (NB*NH)        // 64 (n,h) pairs
#define KVSZ (DD*DD + DD)    // 4160: 64x64 KV + 64 Ksum
#define VSP 2                // v-split: each block computes 32 of 64 v-cols
#define FRAGW 768            // uint4 words of prepacked fragments per pair (12KB)

typedef short v8s __attribute__((ext_vector_type(8)));   // 8 bf16 MFMA operand
typedef float v4f __attribute__((ext_vector_type(4)));   // MFMA accumulator
union U8 { v8s s; unsigned int u[4]; uint4 q; };

__device__ __forceinline__ float fmap(float x) {
    return x > 0.f ? x + 1.f : __expf(x);   // elu+1
}
__device__ __forceinline__ unsigned short bf_hi(float x) {  // RNE fp32->bf16
    unsigned int u = __float_as_uint(x);
    return (unsigned short)((u + 0x7FFFu + ((u >> 16) & 1u)) >> 16);
}
__device__ __forceinline__ float bf_f(unsigned short b) {
    return __uint_as_float(((unsigned int)b) << 16);
}
// hi/lo bf16 split of (x0,x1) via v_cvt_pk_bf16_f32 (RNE, bit-identical to bf_hi):
// .x = hi(x0) | hi(x1)<<16 ; .y = lo(x0) | lo(x1)<<16
__device__ __forceinline__ uint2 packsplit2(float x0, float x1) {
    union { __hip_bfloat162 b; unsigned int u; } h, l;
    h.b = __float22bfloat162_rn(make_float2(x0, x1));
    float r0 = x0 - __uint_as_float(h.u << 16);
    float r1 = x1 - __uint_as_float(h.u & 0xFFFF0000u);
    l.b = __float22bfloat162_rn(make_float2(r0, r1));
    uint2 r; r.x = h.u; r.y = l.u;
    return r;
}
#define MFMA(A, B, C) __builtin_amdgcn_mfma_f32_16x16x32_bf16((A), (B), (C), 0, 0, 0)

// ---------------- Phase 1: partial KV = K^T V via MFMA; Ksum via fp32 VALU --------
// Direct fragment-layout global dword loads (each load-instr covers 4 full 256B
// rows; every element fetched once per wave). load -> cvt_pk pack -> MFMA, all
// in-register: no staging LDS, no barriers in the main loop. Explicit 2-set
// register double buffer; launch_bounds(128,2) (VGPR cap 256 -> no spill).
__global__ __launch_bounds__(128, 2) void kv_partial_kernel(
    const float* __restrict__ K, const float* __restrict__ V,
    const float* __restrict__ kvm, float* __restrict__ partial, int CH)
{
    int bx = blockIdx.x;
    int chunk = bx % CH;
    int vh    = (bx / CH) % VSP;
    int pair  = bx / (CH * VSP);
    int nb = pair >> 3, h = pair & 7;
    int tid = threadIdx.x, w = tid >> 6, lane = tid & 63;
    int g = lane >> 4, c16 = lane & 15;

    __shared__ float scr[2][2048];   // epilogue only
    __shared__ float ksl[2][64];

    v4f acc[4][2];
    float ksum[4] = {0.f, 0.f, 0.f, 0.f};
    v4f z4 = {0.f, 0.f, 0.f, 0.f};
#pragma unroll
    for (int i = 0; i < 4; ++i) { acc[i][0] = z4; acc[i][1] = z4; }

    int SC = SK / CH;
    int nk = SC >> 6;                 // tiles per wave (tile = 32 s-rows)
    int rowbase = nb * SK + chunk * SC;

    float kb0[32], vb0[16], mb0[8];
    float kb1[32], vb1[16], mb1[8];

    // fragment-layout loads: kb[md*8+j] = K[s0+8g+j][16md+c16], coalesced per
    // (j,md): 64 lanes cover 4 rows x 256B, fully consumed across md.
#define LOADT(kb_, vb_, mb_, it_) {                                          \
    const float* kp = K + ((size_t)(rowbase + ((it_) << 5)) * NH + h) * DD;  \
    const float* vp = V + ((size_t)(rowbase + ((it_) << 5)) * NH + h) * DD + vh * 32; \
    const float* mp = kvm + rowbase + ((it_) << 5);                          \
    _Pragma("unroll") for (int j = 0; j < 8; ++j) {                          \
        mb_[j] = mp[8 * g + j];                                              \
        _Pragma("unroll") for (int md = 0; md < 4; ++md)                     \
            kb_[md * 8 + j] = kp[(8 * g + j) * (NH * DD) + md * 16 + c16];   \
        _Pragma("unroll") for (int nn = 0; nn < 2; ++nn)                     \
            vb_[nn * 8 + j] = vp[(8 * g + j) * (NH * DD) + nn * 16 + c16];   \
    } }

#define STEP(kb_, vb_, mb_) {                                                \
    U8 ah[4], al[4], bh[2], bl[2];                                           \
    _Pragma("unroll") for (int md = 0; md < 4; ++md)                         \
        _Pragma("unroll") for (int p = 0; p < 4; ++p) {                      \
            float x0 = fmap(kb_[md * 8 + 2 * p])     * mb_[2 * p];           \
            float x1 = fmap(kb_[md * 8 + 2 * p + 1]) * mb_[2 * p + 1];       \
            ksum[md] += x0 + x1;                                             \
            uint2 pw = packsplit2(x0, x1);                                   \
            ah[md].u[p] = pw.x; al[md].u[p] = pw.y;                          \
        }                                                                    \
    _Pragma("unroll") for (int nn = 0; nn < 2; ++nn)                         \
        _Pragma("unroll") for (int p = 0; p < 4; ++p) {                      \
            float x0 = vb_[nn * 8 + 2 * p]     * mb_[2 * p];                 \
            float x1 = vb_[nn * 8 + 2 * p + 1] * mb_[2 * p + 1];             \
            uint2 pw = packsplit2(x0, x1);                                   \
            bh[nn].u[p] = pw.x; bl[nn].u[p] = pw.y;                          \
        }                                                                    \
    _Pragma("unroll") for (int md = 0; md < 4; ++md)                         \
        _Pragma("unroll") for (int nn = 0; nn < 2; ++nn) {                   \
            acc[md][nn] = MFMA(ah[md].s, bh[nn].s, acc[md][nn]);             \
            acc[md][nn] = MFMA(al[md].s, bh[nn].s, acc[md][nn]);             \
            acc[md][nn] = MFMA(ah[md].s, bl[nn].s, acc[md][nn]);             \
        } }

    LOADT(kb0, vb0, mb0, w);
    if (nk > 1) LOADT(kb1, vb1, mb1, w + 2);
    for (int k = 0; k < nk; k += 2) {
        STEP(kb0, vb0, mb0);
        if (k + 2 < nk) LOADT(kb0, vb0, mb0, w + 2 * (k + 2));
        if (k + 1 < nk) {
            STEP(kb1, vb1, mb1);
            if (k + 3 < nk) LOADT(kb1, vb1, mb1, w + 2 * (k + 3));
        }
    }

    // ---- epilogue ----
    // ksum: reduce over g (lanes differing in bits 4,5)
#pragma unroll
    for (int md = 0; md < 4; ++md) {
        ksum[md] += __shfl_xor(ksum[md], 16);
        ksum[md] += __shfl_xor(ksum[md], 32);
    }
    if (lane < 16)
#pragma unroll
        for (int md = 0; md < 4; ++md) ksl[w][md * 16 + c16] = ksum[md];

    // acc: C layout col=lane&15 (v), row=4*(lane>>4)+jj (d)
#pragma unroll
    for (int md = 0; md < 4; ++md)
#pragma unroll
        for (int nn = 0; nn < 2; ++nn)
#pragma unroll
            for (int jj = 0; jj < 4; ++jj)
                scr[w][(16 * md + 4 * g + jj) * 32 + 16 * nn + c16] = acc[md][nn][jj];
    __syncthreads();

    float* dst = partial + ((size_t)chunk * NPAIR + pair) * KVSZ;
    if (vh == 0 && tid < 64) dst[4096 + tid] = ksl[0][tid] + ksl[1][tid];
    {
        int i0 = tid * 16;
#pragma unroll
        for (int e = 0; e < 4; ++e) {
            int idx = i0 + 4 * e;
            float4 x = *(float4*)&scr[0][idx];
            float4 y = *(float4*)&scr[1][idx];
            int d = idx >> 5, v = idx & 31;
            *(float4*)&dst[d * 64 + vh * 32 + v] =
                make_float4(x.x + y.x, x.y + y.y, x.z + y.z, x.w + y.w);
        }
    }
#undef LOADT
#undef STEP
}

// ---------------- Phase 1b: reduce partials over chunks -----------------
__global__ __launch_bounds__(256) void kv_reduce_kernel(
    const float* __restrict__ partial, float* __restrict__ kvf, int CH)
{
    int i = blockIdx.x * 256 + threadIdx.x;
    if (i >= NPAIR * KVSZ) return;
    float s = 0.f;
    for (int c = 0; c < CH; ++c) s += partial[(size_t)c * NPAIR * KVSZ + i];
    kvf[i] = s;
}

// ---------------- Phase 1c: prepack B fragments (bf16) for attn_out --------
__global__ __launch_bounds__(256) void kv_pack_kernel(
    const float* __restrict__ kvf, uint4* __restrict__ frag)
{
    int pair = blockIdx.x;
    int t = threadIdx.x;
    __shared__ float kvr[KVSZ];
    const float* src = kvf + (size_t)pair * KVSZ;
    for (int e = t; e < KVSZ / 4; e += 256)
        *(float4*)&kvr[4 * e] = *(const float4*)(src + 4 * e);
    __syncthreads();

    for (int e = t; e < FRAGW; e += 256) {
        int i4 = e >> 6, lane = e & 63;
        int g = lane >> 4, c16 = lane & 15;
        unsigned int wd[4];
        if (i4 < 8) {
            int ks = i4 >> 2, nn = i4 & 3;
#pragma unroll
            for (int p = 0; p < 4; ++p) {
                float x0 = kvr[(32 * ks + 8 * g + 2 * p) * 64 + 16 * nn + c16];
                float x1 = kvr[(32 * ks + 8 * g + 2 * p + 1) * 64 + 16 * nn + c16];
                wd[p] = (unsigned int)bf_hi(x0) | ((unsigned int)bf_hi(x1) << 16);
            }
        } else {
            int j = i4 - 8, ks = j & 1, lo = j >> 1;
#pragma unroll
            for (int p = 0; p < 4; ++p) {
                unsigned int wp = 0;
                if (c16 == 0) {
                    float x0 = kvr[4096 + 32 * ks + 8 * g + 2 * p];
                    float x1 = kvr[4096 + 32 * ks + 8 * g + 2 * p + 1];
                    unsigned short h0 = bf_hi(x0), h1 = bf_hi(x1);
                    if (lo)
                        wp = (unsigned int)bf_hi(x0 - bf_f(h0)) |
                             ((unsigned int)bf_hi(x1 - bf_f(h1)) << 16);
                    else
                        wp = (unsigned int)h0 | ((unsigned int)h1 << 16);
                }
                wd[p] = wp;
            }
        }
        uint4 o; o.x = wd[0]; o.y = wd[1]; o.z = wd[2]; o.w = wd[3];
        frag[(size_t)pair * FRAGW + e] = o;
    }
}

// ---------------- Phase 2: out = (q.KV)/(q.Ksum + eps) via MFMA, no LDS --------
__global__ __launch_bounds__(256) void attn_out_kernel(
    const float* __restrict__ Q, const float* __restrict__ qm,
    const uint4* __restrict__ frag, float* __restrict__ out)
{
    int bx = blockIdx.x;
    int pair = bx >> 5;            // 32 consecutive blocks share a pair (L2)
    int rb   = bx & 31;            // 128-row group
    int nb = pair >> 3, h = pair & 7;
    int lane = threadIdx.x & 63;
    int w    = threadIdx.x >> 6;
    int g    = lane >> 4;
    int c16  = lane & 15;

    const uint4* fb = frag + (size_t)pair * FRAGW;
    U8 Bh[2][4], Bkh[2], Bkl[2];
#pragma unroll
    for (int ks = 0; ks < 2; ++ks)
#pragma unroll
        for (int nn = 0; nn < 4; ++nn)
            Bh[ks][nn].q = fb[(ks * 4 + nn) * 64 + lane];
    Bkh[0].q = fb[8 * 64 + lane];
    Bkh[1].q = fb[9 * 64 + lane];
    Bkl[0].q = fb[10 * 64 + lane];
    Bkl[1].q = fb[11 * 64 + lane];

    float4 qA[2][4];
    float qmA[2];

    auto QLOAD = [&](int it, float4* qr, float& qmv) {
        int row = rb * 128 + (w + 4 * it) * 16 + c16;
        qmv = qm[nb * LQ + row];
        const float* qrow = Q + ((size_t)((nb * LQ + row) * NH + h)) * DD;
        qr[0] = *(const float4*)(qrow + 8 * g);
        qr[1] = *(const float4*)(qrow + 8 * g + 4);
        qr[2] = *(const float4*)(qrow + 8 * g + 32);
        qr[3] = *(const float4*)(qrow + 8 * g + 36);
    };

    v4f z4 = {0.f, 0.f, 0.f, 0.f};
    QLOAD(0, qA[0], qmA[0]);
#pragma unroll
    for (int it = 0; it < 2; ++it) {
        if (it == 0) QLOAD(1, qA[1], qmA[1]);   // prefetch under pack+MFMA
        const float4* qr = qA[it];
        float qmv = qmA[it];

        U8 Ah[2], Al[2];
#pragma unroll
        for (int ks = 0; ks < 2; ++ks) {
            float qv[8] = {qr[2*ks].x, qr[2*ks].y, qr[2*ks].z, qr[2*ks].w,
                           qr[2*ks+1].x, qr[2*ks+1].y, qr[2*ks+1].z, qr[2*ks+1].w};
#pragma unroll
            for (int p = 0; p < 4; ++p) {
                uint2 pw = packsplit2(fmap(qv[2*p]) * qmv, fmap(qv[2*p+1]) * qmv);
                Ah[ks].u[p] = pw.x;
                Al[ks].u[p] = pw.y;
            }
        }

        v4f a0 = z4, a1 = z4, a2 = z4, a3 = z4, a4 = z4;
#pragma unroll
        for (int ks = 0; ks < 2; ++ks) {
            a0 = MFMA(Ah[ks].s, Bh[ks][0].s, a0);
            a1 = MFMA(Ah[ks].s, Bh[ks][1].s, a1);
            a2 = MFMA(Ah[ks].s, Bh[ks][2].s, a2);
            a3 = MFMA(Ah[ks].s, Bh[ks][3].s, a3);
            a0 = MFMA(Al[ks].s, Bh[ks][0].s, a0);
            a1 = MFMA(Al[ks].s, Bh[ks][1].s, a1);
            a2 = MFMA(Al[ks].s, Bh[ks][2].s, a2);
            a3 = MFMA(Al[ks].s, Bh[ks][3].s, a3);
            a4 = MFMA(Ah[ks].s, Bkh[ks].s, a4);
            a4 = MFMA(Al[ks].s, Bkh[ks].s, a4);
            a4 = MFMA(Ah[ks].s, Bkl[ks].s, a4);
        }

        int row0 = rb * 128 + (w + 4 * it) * 16;
        int src = lane & 48;
#pragma unroll
        for (int jj = 0; jj < 4; ++jj) {
            float den = __shfl(a4[jj], src);
            float z = 1.f / (den + 1e-6f);
            size_t ob = ((size_t)((nb * LQ + row0 + 4 * g + jj) * NH + h)) * DD + c16;
            out[ob]      = a0[jj] * z;
            out[ob + 16] = a1[jj] * z;
            out[ob + 32] = a2[jj] * z;
            out[ob + 48] = a3[jj] * z;
        }
    }
}

extern "C" void kernel_launch(void* const* d_in, const int* in_sizes, int n_in,
                              void* d_out, int out_size, void* d_ws, size_t ws_size,
                              hipStream_t stream) {
    const float* Q   = (const float*)d_in[0];
    const float* K   = (const float*)d_in[1];
    const float* V   = (const float*)d_in[2];
    const float* qm  = (const float*)d_in[3];
    const float* kvm = (const float*)d_in[4];
    float* out = (float*)d_out;

    int CH = 16;
    while (CH > 1 && (size_t)(CH + 1) * NPAIR * KVSZ * sizeof(float) > ws_size) CH >>= 1;

    float* partial = (float*)d_ws;
    float* kvf = partial + (size_t)CH * NPAIR * KVSZ;
    // frag overlays partial slab 0 (partial is dead once kv_reduce has run)
    uint4* frag = (uint4*)d_ws;

    kv_partial_kernel<<<dim3(NPAIR * CH * VSP), dim3(128), 0, stream>>>(K, V, kvm, partial, CH);
    kv_reduce_kernel<<<dim3((NPAIR * KVSZ + 255) / 256), dim3(256), 0, stream>>>(partial, kvf, CH);
    kv_pack_kernel<<<dim3(NPAIR), dim3(256), 0, stream>>>(kvf, frag);
    attn_out_kernel<<<dim3(NPAIR * 32), dim3(256), 0, stream>>>(Q, qm, frag, out);
}

// Round 9
// 81.931 us; speedup vs baseline: 1.6321x; 1.2687x over previous
//
#include <hip/hip_runtime.h>
#include <hip/hip_bf16.h>

#define NB 8
#define LQ 4096
#define SK 4096
#define NH 8
#define DD 64
#define NPAIR (NB*NH)        // 64 (n,h) pairs
#define KVSZ (DD*DD + DD)    // 4160: 64x64 KV + 64 Ksum
#define FRAGW 768            // uint4 words of prepacked fragments per pair (12KB)

typedef short v8s __attribute__((ext_vector_type(8)));   // 8 bf16 MFMA operand
typedef float v4f __attribute__((ext_vector_type(4)));   // MFMA accumulator
union U8 { v8s s; unsigned int u[4]; uint4 q; };

__device__ __forceinline__ float fmap(float x) {
    return x > 0.f ? x + 1.f : __expf(x);   // elu+1
}
__device__ __forceinline__ unsigned short bf_hi(float x) {  // RNE fp32->bf16
    unsigned int u = __float_as_uint(x);
    return (unsigned short)((u + 0x7FFFu + ((u >> 16) & 1u)) >> 16);
}
__device__ __forceinline__ float bf_f(unsigned short b) {
    return __uint_as_float(((unsigned int)b) << 16);
}
// hi/lo bf16 split of (x0,x1) via v_cvt_pk_bf16_f32 (RNE, bit-identical to bf_hi)
__device__ __forceinline__ uint2 packsplit2(float x0, float x1) {
    union { __hip_bfloat162 b; unsigned int u; } h, l;
    h.b = __float22bfloat162_rn(make_float2(x0, x1));
    float r0 = x0 - __uint_as_float(h.u << 16);
    float r1 = x1 - __uint_as_float(h.u & 0xFFFF0000u);
    l.b = __float22bfloat162_rn(make_float2(r0, r1));
    uint2 r; r.x = h.u; r.y = l.u;
    return r;
}
#define MFMA(A, B, C) __builtin_amdgcn_mfma_f32_16x16x32_bf16((A), (B), (C), 0, 0, 0)

// async global->LDS, 16B per lane: LDS dest = uniform base + lane*16 (linear);
// global source is per-lane (pre-swizzled to realize the LDS bank swizzle).
__device__ __forceinline__ void gload16(const float* g, float* lds) {
    __builtin_amdgcn_global_load_lds(
        (const __attribute__((address_space(1))) unsigned int*)g,
        (__attribute__((address_space(3))) unsigned int*)lds, 16, 0, 0);
}

// ---------------- Phase 1: partial KV = K^T V via MFMA --------------------
// Block = 256 thr = 4 waves, one (pair, s-chunk); wave w owns output rows
// 16w..16w+15 (acc = 4 v4f only). Double-buffered raw-f32 LDS tiles staged by
// global_load_lds (zero staging VGPRs). Row swizzle d_phys = d ^ ((s>>3&1)<<4)
// -> fragment ds_read_b32 is 2 lanes/bank (free), staging stays coalesced.
// 2-phase pipeline: STAGE(next) -> COMPUTE(cur) -> barrier (one vmcnt drain/tile).
__global__ __launch_bounds__(256, 3) void kv_partial_kernel(
    const float* __restrict__ K, const float* __restrict__ V,
    const float* __restrict__ kvm, float* __restrict__ partial, int CH)
{
    int bx = blockIdx.x;
    int chunk = bx % CH;
    int pair  = bx / CH;
    int nb = pair >> 3, h = pair & 7;
    int tid = threadIdx.x, w = tid >> 6, lane = tid & 63;
    int g = lane >> 4, c16 = lane & 15;

    __shared__ float Kl[2][2048];   // [buf][s*64 + d_phys]
    __shared__ float Vl[2][2048];

    v4f acc[4];                      // [nn] -> D rows 16w+4g+jj, cols 16nn+c16
    v4f z4 = {0.f, 0.f, 0.f, 0.f};
#pragma unroll
    for (int nn = 0; nn < 4; ++nn) acc[nn] = z4;
    float ksum = 0.f;

    int SC = SK / CH;
    int tiles = SC >> 5;             // 32-row tiles (even: 8 at CH=16)
    int rowbase = nb * SK + chunk * SC;

    // staging geometry (per wave: 2 instrs K + 2 instrs V, 4 rows each)
    int srow0 = (lane >> 4);         // row within 4-row group
    int dp    = (lane & 15) << 2;    // phys col base (dwords)

    auto STAGE = [&](int b, int t) {
#pragma unroll
        for (int i = 0; i < 2; ++i) {
            int I = 2 * w + i;                       // instr id 0..7
            int s = I * 4 + srow0;                   // row 0..31
            int dl = dp ^ (((s >> 3) & 1) << 4);     // logical col (4-run safe)
            size_t gb = (size_t)(rowbase + (t << 5) + s) * (NH * DD) + h * DD + dl;
            gload16(K + gb, &Kl[b][I * 256]);
            gload16(V + gb, &Vl[b][I * 256]);
        }
    };

    auto COMPUTE = [&](int b, const float* mr) {
        // A fragment: K column d = 16w + c16, s-slice 8g..8g+7
        float xa[8];
#pragma unroll
        for (int j = 0; j < 8; ++j) {
            int s = 8 * g + j;
            float kv_ = Kl[b][s * 64 + ((16 * w + c16) ^ (((s >> 3) & 1) << 4))];
            xa[j] = fmap(kv_) * mr[j];
            ksum += xa[j];
        }
        U8 ah, al;
#pragma unroll
        for (int p = 0; p < 4; ++p) {
            uint2 pw = packsplit2(xa[2 * p], xa[2 * p + 1]);
            ah.u[p] = pw.x; al.u[p] = pw.y;
        }
#pragma unroll
        for (int nn = 0; nn < 4; ++nn) {
            float xb[8];
#pragma unroll
            for (int j = 0; j < 8; ++j) {
                int s = 8 * g + j;
                xb[j] = Vl[b][s * 64 + ((16 * nn + c16) ^ (((s >> 3) & 1) << 4))] * mr[j];
            }
            U8 bh, bl;
#pragma unroll
            for (int p = 0; p < 4; ++p) {
                uint2 pw = packsplit2(xb[2 * p], xb[2 * p + 1]);
                bh.u[p] = pw.x; bl.u[p] = pw.y;
            }
            acc[nn] = MFMA(ah.s, bh.s, acc[nn]);
            acc[nn] = MFMA(al.s, bh.s, acc[nn]);
            acc[nn] = MFMA(ah.s, bl.s, acc[nn]);
        }
    };

    float mr0[8], mr1[8];
    auto MLOADR = [&](float* mr, int t) {
#pragma unroll
        for (int j = 0; j < 8; ++j)
            mr[j] = kvm[rowbase + (t << 5) + 8 * g + j];
    };

    STAGE(0, 0); MLOADR(mr0, 0);
    __syncthreads();                         // vmcnt(0) drain by compiler
    for (int t = 0; t < tiles; t += 2) {
        if (t + 1 < tiles) { STAGE(1, t + 1); MLOADR(mr1, t + 1); }
        COMPUTE(0, mr0);
        __syncthreads();                     // next tile landed under COMPUTE
        if (t + 1 < tiles) {
            if (t + 2 < tiles) { STAGE(0, t + 2); MLOADR(mr0, t + 2); }
            COMPUTE(1, mr1);
            __syncthreads();
        }
    }

    // ---- epilogue: wave-private output rows -> direct global stores ----
    ksum += __shfl_xor(ksum, 16);
    ksum += __shfl_xor(ksum, 32);
    float* dst = partial + ((size_t)chunk * NPAIR + pair) * KVSZ;
    if (lane < 16) dst[4096 + 16 * w + c16] = ksum;
#pragma unroll
    for (int nn = 0; nn < 4; ++nn)
#pragma unroll
        for (int jj = 0; jj < 4; ++jj)
            dst[(16 * w + 4 * g + jj) * 64 + 16 * nn + c16] = acc[nn][jj];
}

// ---------------- Phase 1b: reduce partials over chunks -----------------
__global__ __launch_bounds__(256) void kv_reduce_kernel(
    const float* __restrict__ partial, float* __restrict__ kvf, int CH)
{
    int i = blockIdx.x * 256 + threadIdx.x;
    if (i >= NPAIR * KVSZ) return;
    float s = 0.f;
    for (int c = 0; c < CH; ++c) s += partial[(size_t)c * NPAIR * KVSZ + i];
    kvf[i] = s;
}

// ---------------- Phase 1c: prepack B fragments (bf16) for attn_out --------
__global__ __launch_bounds__(256) void kv_pack_kernel(
    const float* __restrict__ kvf, uint4* __restrict__ frag)
{
    int pair = blockIdx.x;
    int t = threadIdx.x;
    __shared__ float kvr[KVSZ];
    const float* src = kvf + (size_t)pair * KVSZ;
    for (int e = t; e < KVSZ / 4; e += 256)
        *(float4*)&kvr[4 * e] = *(const float4*)(src + 4 * e);
    __syncthreads();

    for (int e = t; e < FRAGW; e += 256) {
        int i4 = e >> 6, lane = e & 63;
        int g = lane >> 4, c16 = lane & 15;
        unsigned int wd[4];
        if (i4 < 8) {
            int ks = i4 >> 2, nn = i4 & 3;
#pragma unroll
            for (int p = 0; p < 4; ++p) {
                float x0 = kvr[(32 * ks + 8 * g + 2 * p) * 64 + 16 * nn + c16];
                float x1 = kvr[(32 * ks + 8 * g + 2 * p + 1) * 64 + 16 * nn + c16];
                wd[p] = (unsigned int)bf_hi(x0) | ((unsigned int)bf_hi(x1) << 16);
            }
        } else {
            int j = i4 - 8, ks = j & 1, lo = j >> 1;
#pragma unroll
            for (int p = 0; p < 4; ++p) {
                unsigned int wp = 0;
                if (c16 == 0) {
                    float x0 = kvr[4096 + 32 * ks + 8 * g + 2 * p];
                    float x1 = kvr[4096 + 32 * ks + 8 * g + 2 * p + 1];
                    unsigned short h0 = bf_hi(x0), h1 = bf_hi(x1);
                    if (lo)
                        wp = (unsigned int)bf_hi(x0 - bf_f(h0)) |
                             ((unsigned int)bf_hi(x1 - bf_f(h1)) << 16);
                    else
                        wp = (unsigned int)h0 | ((unsigned int)h1 << 16);
                }
                wd[p] = wp;
            }
        }
        uint4 o; o.x = wd[0]; o.y = wd[1]; o.z = wd[2]; o.w = wd[3];
        frag[(size_t)pair * FRAGW + e] = o;
    }
}

// ---------------- Phase 2: out = (q.KV)/(q.Ksum + eps) via MFMA, no LDS --------
__global__ __launch_bounds__(256) void attn_out_kernel(
    const float* __restrict__ Q, const float* __restrict__ qm,
    const uint4* __restrict__ frag, float* __restrict__ out)
{
    int bx = blockIdx.x;
    int pair = bx >> 5;            // 32 consecutive blocks share a pair (L2)
    int rb   = bx & 31;            // 128-row group
    int nb = pair >> 3, h = pair & 7;
    int lane = threadIdx.x & 63;
    int w    = threadIdx.x >> 6;
    int g    = lane >> 4;
    int c16  = lane & 15;

    const uint4* fb = frag + (size_t)pair * FRAGW;
    U8 Bh[2][4], Bkh[2], Bkl[2];
#pragma unroll
    for (int ks = 0; ks < 2; ++ks)
#pragma unroll
        for (int nn = 0; nn < 4; ++nn)
            Bh[ks][nn].q = fb[(ks * 4 + nn) * 64 + lane];
    Bkh[0].q = fb[8 * 64 + lane];
    Bkh[1].q = fb[9 * 64 + lane];
    Bkl[0].q = fb[10 * 64 + lane];
    Bkl[1].q = fb[11 * 64 + lane];

    float4 qA[2][4];
    float qmA[2];

    auto QLOAD = [&](int it, float4* qr, float& qmv) {
        int row = rb * 128 + (w + 4 * it) * 16 + c16;
        qmv = qm[nb * LQ + row];
        const float* qrow = Q + ((size_t)((nb * LQ + row) * NH + h)) * DD;
        qr[0] = *(const float4*)(qrow + 8 * g);
        qr[1] = *(const float4*)(qrow + 8 * g + 4);
        qr[2] = *(const float4*)(qrow + 8 * g + 32);
        qr[3] = *(const float4*)(qrow + 8 * g + 36);
    };

    v4f z4 = {0.f, 0.f, 0.f, 0.f};
    QLOAD(0, qA[0], qmA[0]);
#pragma unroll
    for (int it = 0; it < 2; ++it) {
        if (it == 0) QLOAD(1, qA[1], qmA[1]);   // prefetch under pack+MFMA
        const float4* qr = qA[it];
        float qmv = qmA[it];

        U8 Ah[2], Al[2];
#pragma unroll
        for (int ks = 0; ks < 2; ++ks) {
            float qv[8] = {qr[2*ks].x, qr[2*ks].y, qr[2*ks].z, qr[2*ks].w,
                           qr[2*ks+1].x, qr[2*ks+1].y, qr[2*ks+1].z, qr[2*ks+1].w};
#pragma unroll
            for (int p = 0; p < 4; ++p) {
                uint2 pw = packsplit2(fmap(qv[2*p]) * qmv, fmap(qv[2*p+1]) * qmv);
                Ah[ks].u[p] = pw.x;
                Al[ks].u[p] = pw.y;
            }
        }

        v4f a0 = z4, a1 = z4, a2 = z4, a3 = z4, a4 = z4;
#pragma unroll
        for (int ks = 0; ks < 2; ++ks) {
            a0 = MFMA(Ah[ks].s, Bh[ks][0].s, a0);
            a1 = MFMA(Ah[ks].s, Bh[ks][1].s, a1);
            a2 = MFMA(Ah[ks].s, Bh[ks][2].s, a2);
            a3 = MFMA(Ah[ks].s, Bh[ks][3].s, a3);
            a0 = MFMA(Al[ks].s, Bh[ks][0].s, a0);
            a1 = MFMA(Al[ks].s, Bh[ks][1].s, a1);
            a2 = MFMA(Al[ks].s, Bh[ks][2].s, a2);
            a3 = MFMA(Al[ks].s, Bh[ks][3].s, a3);
            a4 = MFMA(Ah[ks].s, Bkh[ks].s, a4);
            a4 = MFMA(Al[ks].s, Bkh[ks].s, a4);
            a4 = MFMA(Ah[ks].s, Bkl[ks].s, a4);
        }

        int row0 = rb * 128 + (w + 4 * it) * 16;
        int src = lane & 48;
#pragma unroll
        for (int jj = 0; jj < 4; ++jj) {
            float den = __shfl(a4[jj], src);
            float z = 1.f / (den + 1e-6f);
            size_t ob = ((size_t)((nb * LQ + row0 + 4 * g + jj) * NH + h)) * DD + c16;
            out[ob]      = a0[jj] * z;
            out[ob + 16] = a1[jj] * z;
            out[ob + 32] = a2[jj] * z;
            out[ob + 48] = a3[jj] * z;
        }
    }
}

extern "C" void kernel_launch(void* const* d_in, const int* in_sizes, int n_in,
                              void* d_out, int out_size, void* d_ws, size_t ws_size,
                              hipStream_t stream) {
    const float* Q   = (const float*)d_in[0];
    const float* K   = (const float*)d_in[1];
    const float* V   = (const float*)d_in[2];
    const float* qm  = (const float*)d_in[3];
    const float* kvm = (const float*)d_in[4];
    float* out = (float*)d_out;

    int CH = 16;
    while (CH > 1 && (size_t)(CH + 1) * NPAIR * KVSZ * sizeof(float) > ws_size) CH >>= 1;

    float* partial = (float*)d_ws;
    float* kvf = partial + (size_t)CH * NPAIR * KVSZ;
    // frag overlays partial slab 0 (partial is dead once kv_reduce has run)
    uint4* frag = (uint4*)d_ws;

    kv_partial_kernel<<<dim3(NPAIR * CH), dim3(256), 0, stream>>>(K, V, kvm, partial, CH);
    kv_reduce_kernel<<<dim3((NPAIR * KVSZ + 255) / 256), dim3(256), 0, stream>>>(partial, kvf, CH);
    kv_pack_kernel<<<dim3(NPAIR), dim3(256), 0, stream>>>(kvf, frag);
    attn_out_kernel<<<dim3(NPAIR * 32), dim3(256), 0, stream>>>(Q, qm, frag, out);
}